// Round 18
// baseline (814.824 us; speedup 1.0000x reference)
//
#include <hip/hip_runtime.h>
#include <stdint.h>

typedef unsigned int u32;
using i32x4 = __attribute__((ext_vector_type(4))) int;

// async global->LDS, 16B per lane, dest = wave-uniform base + lane*16
#define GLD_LDS16(SRC, DST)                                      \
  __builtin_amdgcn_global_load_lds(                              \
      (const __attribute__((address_space(1))) void*)(SRC),      \
      (__attribute__((address_space(3))) void*)(DST), 16, 0, 0)

#define SCHED0() __builtin_amdgcn_sched_barrier(0)
#define BAR()    __builtin_amdgcn_s_barrier()
#define PRIO(x)  __builtin_amdgcn_s_setprio(x)

// ---------- pass 1: per-row symmetric int8 quant (x rows, then w rows) ----------
__global__ __launch_bounds__(256)
void quant_rows(const float* __restrict__ x, const float* __restrict__ w,
                signed char* __restrict__ xq, signed char* __restrict__ wq,
                float* __restrict__ sx, float* __restrict__ sw,
                int Mrows, int totRows, int K) {
  __shared__ float red[4];
  for (int row = blockIdx.x; row < totRows; row += gridDim.x) {
    const bool isx = row < Mrows;
    const float* src = isx ? x + (size_t)row * K : w + (size_t)(row - Mrows) * K;
    const float4* s4 = reinterpret_cast<const float4*>(src) + threadIdx.x * 4;
    float4 v[4];
#pragma unroll
    for (int g = 0; g < 4; ++g) v[g] = s4[g];
    float am = 0.f;
#pragma unroll
    for (int g = 0; g < 4; ++g)
      am = fmaxf(am, fmaxf(fmaxf(fabsf(v[g].x), fabsf(v[g].y)),
                           fmaxf(fabsf(v[g].z), fabsf(v[g].w))));
#pragma unroll
    for (int m = 1; m <= 32; m <<= 1) am = fmaxf(am, __shfl_xor(am, m));
    if ((threadIdx.x & 63) == 0) red[threadIdx.x >> 6] = am;
    __syncthreads();
    am = fmaxf(fmaxf(red[0], red[1]), fmaxf(red[2], red[3]));
    const float s   = am > 0.f ? am * (1.f / 127.f) : 1.f;
    const float inv = am > 0.f ? 127.f / am : 0.f;
    u32 pk[4];
#pragma unroll
    for (int g = 0; g < 4; ++g) {
      const float* vp = reinterpret_cast<const float*>(&v[g]);
      u32 p = 0;
#pragma unroll
      for (int e = 0; e < 4; ++e) {
        int q = (int)rintf(vp[e] * inv);
        q = q < -127 ? -127 : (q > 127 ? 127 : q);
        p |= ((u32)(q & 0xff)) << (8 * e);
      }
      pk[g] = p;
    }
    signed char* dst = (isx ? xq + (size_t)row * K : wq + (size_t)(row - Mrows) * K)
                       + threadIdx.x * 16;
    *reinterpret_cast<uint4*>(dst) = make_uint4(pk[0], pk[1], pk[2], pk[3]);
    if (threadIdx.x == 0) { if (isx) sx[row] = s; else sw[row - Mrows] = s; }
    __syncthreads();
  }
}

// ---------- pass 2: int8 GEMM, 128x128 tile, 2 INDEPENDENT WGS PER CU ----------
// The r9 structure scaled to 4 waves (2M x 2N, 64x64/wave) with 64 KiB LDS/wg so
// TWO 256-thread wgs co-reside per CU (launch_bounds(256,2) -> 256-reg cap; r6's
// spill bug was the (512,4)=128-reg cap). Each wg places 1 wave/SIMD -> every SIMD
// holds waves from two different barrier domains: while wg0's waves sit in a
// read/stage window, wg1's waves keep the matrix pipe fed (m114 co-scheduling) --
// the only overlap mechanism not yet tested against the serial-pipe plateau.
// Swizzle/addressing/ledger byte-identical per-row to verified r9 (0 conflicts,
// absmax bit-stable 0.1015625): rows 128B, phys_slot=(ks*4+kq)^(row&7).
// Per tile (2 phases):
//  P0: BAR | rd afB(A,ks1):4 | stage B(t+2)->cur:4 | C1: 16 MFMA ks0 (afA x bP)
//      | vmcnt(4)  [drains B(t+1),A(t+1); leaves B(t+2)]
//  P1: BAR | C2a: 8 MFMA ks1 (afB x bQ[0,1]) | rd afA(t+1,ks0):4, bP(t+1,ks0):4
//      | stage A(t+2)->cur:4 | C2b: 8 MFMA ks1 (bQ[2,3]) | rd bQ(t+1,ks1):4
// All B(t) frag reads (bP,bQ) happen in t-1 P1 -> stage-B(t+2) in P0 is 1-barrier
// separated from last reads (r9's WAR discipline). Gate ledger: entry
// [B(t+1):4, A(t+1):4]; P0 +B(t+2) -> vmcnt(4) leaves B(t+2). Steady.
__global__ __launch_bounds__(256, 2)
void gemm_i8_2wg(const signed char* __restrict__ A,   // [M][K] i8
                 const signed char* __restrict__ B,   // [N][K] i8
                 const float* __restrict__ sx,        // [M]
                 const float* __restrict__ sw,        // [N]
                 const float* __restrict__ wscale_p,  // [1]
                 const float* __restrict__ bias,      // [N]
                 float* __restrict__ C,               // [M][N] fp32
                 int Nn, int Kk, int NT) {
  __shared__ signed char lds[2][2][128 * 128];   // 64 KiB -> 2 wgs/CU

  const int tid  = threadIdx.x;
  const int lane = tid & 63;
  const int wave = tid >> 6;       // 0..3
  const int wr = wave >> 1;        // 0..1 (M)
  const int wc = wave & 1;         // 0..1 (N)

  // XCD-aware swizzle (gridDim.x == 8192, divisible by 8)
  const int bid = blockIdx.x;
  const int cpx = gridDim.x >> 3;
  const int wg  = (bid & 7) * cpx + (bid >> 3);
  const int mt = wg / NT, nt = wg % NT;
  const int m0 = mt * 128, n0 = nt * 128;

  // staging: per gload instr, 64 lanes = 8 rows x 128B; lane l -> row l>>3, slot l&7
  const int srow = lane >> 3;
  const int ss   = (lane & 7) ^ (srow & 7);   // inverse-swizzled source k-slot
  const int r16  = lane & 15;
  const int kq   = lane >> 4;

  // per-wave staging slice: 32 rows of A and of B (4 waves cover 128)
  const signed char* ga = A + ((size_t)m0 + wave * 32 + srow) * Kk + ss * 16;
  const signed char* gb = B + ((size_t)n0 + wave * 32 + srow) * Kk + ss * 16;

  // fragment byte offsets: row*128 + ((kq ^ (row&7))<<4); ks=1 flips byte bit 6
  const int aoff = (wr * 64 + r16) * 128 + ((kq ^ (r16 & 7)) << 4);
  const int boff = (wc * 64 + r16) * 128 + ((kq ^ (r16 & 7)) << 4);

  i32x4 acc[4][4];
#pragma unroll
  for (int i = 0; i < 4; ++i)
#pragma unroll
    for (int j = 0; j < 4; ++j)
      acc[i][j] = (i32x4){0, 0, 0, 0};

  i32x4 afA[4], afB[4];   // A frags ks0 / ks1
  i32x4 bP[4], bQ[4];     // B frags ks0 / ks1

  // stage one operand tile (16KB/wg = 4 gloads/wave): op (0=A,1=B) -> lds[bfi], kt
#define STAGE1(bfi_, op_, kt_) do {                                             \
    const signed char* _g = ((op_) ? gb : ga) + (size_t)(kt_) * 128;            \
    signed char* _d = &lds[bfi_][op_][wave * 32 * 128];                         \
    GLD_LDS16(_g,                    _d);                                       \
    GLD_LDS16(_g + (size_t)8  * Kk,  _d + 1024);                                \
    GLD_LDS16(_g + (size_t)16 * Kk,  _d + 2048);                                \
    GLD_LDS16(_g + (size_t)24 * Kk,  _d + 3072);                                \
  } while (0)

#define LDFA(AF_, la_, ks_) do {                                                \
    _Pragma("unroll") for (int _i = 0; _i < 4; ++_i)                            \
      AF_[_i] = *reinterpret_cast<const i32x4*>(                                \
          (la_) + ((aoff + _i * 2048) ^ ((ks_) << 6)));                         \
  } while (0)

#define LDFB(BF_, lb_, ks_) do {                                                \
    _Pragma("unroll") for (int _n = 0; _n < 4; ++_n)                            \
      BF_[_n] = *reinterpret_cast<const i32x4*>(                                \
          (lb_) + ((boff + _n * 2048) ^ ((ks_) << 6)));                         \
  } while (0)

#define MFMA16(AF_, BF_)                                                        \
  _Pragma("unroll") for (int _i = 0; _i < 4; ++_i)                              \
  _Pragma("unroll") for (int _n = 0; _n < 4; ++_n)                              \
    acc[_i][_n] = __builtin_amdgcn_mfma_i32_16x16x64_i8(                        \
        AF_[_i], BF_[_n], acc[_i][_n], 0, 0, 0)

#define MFMA8(AF_, BF_, nlo_)                                                   \
  _Pragma("unroll") for (int _i = 0; _i < 4; ++_i)                              \
  _Pragma("unroll") for (int _n = 0; _n < 2; ++_n)                              \
    acc[_i][(nlo_) + _n] = __builtin_amdgcn_mfma_i32_16x16x64_i8(               \
        AF_[_i], BF_[(nlo_) + _n], acc[_i][(nlo_) + _n], 0, 0, 0)

  const int KT = Kk >> 7;   // K/128 = 32

  // ---- prologue: t0->buf0, t1->buf1; drain t0; pre-read afA,bP,bQ of t0 ----
  STAGE1(0, 0, 0); STAGE1(0, 1, 0);
  STAGE1(1, 0, 1); STAGE1(1, 1, 1);
  asm volatile("s_waitcnt vmcnt(8)" ::: "memory");
  SCHED0(); BAR(); SCHED0();
  LDFA(afA, (const signed char*)&lds[0][0][0], 0);
  LDFB(bP,  (const signed char*)&lds[0][1][0], 0);
  LDFB(bQ,  (const signed char*)&lds[0][1][0], 1);

#define TILE(t_, CUR_) do {                                                     \
    const signed char* laC = &lds[CUR_][0][0];                                  \
    const signed char* laN = &lds[(CUR_) ^ 1][0][0];                            \
    const signed char* lbN = &lds[(CUR_) ^ 1][1][0];                            \
    const int kt2 = ((t_) + 2 < KT) ? (t_) + 2 : KT - 1;                        \
    /* P0 */                                                                    \
    SCHED0(); BAR(); SCHED0();                                                  \
    LDFA(afB, laC, 1);                        /* A ks1 */                       \
    STAGE1(CUR_, 1, kt2);                     /* B(t+2)->cur (B(t) reads were   \
                                                 in t-1 P1, 1 barrier ago) */   \
    PRIO(1); MFMA16(afA, bP); PRIO(0);        /* C1: ks0 */                     \
    SCHED0();                                                                   \
    asm volatile("s_waitcnt vmcnt(4)" ::: "memory");  /* drains A,B(t+1) */     \
    /* P1 */                                                                    \
    SCHED0(); BAR(); SCHED0();                                                  \
    PRIO(1); MFMA8(afB, bQ, 0); PRIO(0);      /* C2a: ks1, ni0-1 */             \
    LDFA(afA, laN, 0);                        /* pre-read t+1 */                \
    LDFB(bP, lbN, 0);                                                           \
    STAGE1(CUR_, 0, kt2);                     /* A(t+2)->cur */                 \
    PRIO(1); MFMA8(afB, bQ, 2); PRIO(0);      /* C2b: ks1, ni2-3 */             \
    LDFB(bQ, lbN, 1);                         /* bQ dead only after C2b */      \
  } while (0)

  for (int t = 0; t < KT; t += 2) {
    TILE(t,     0);
    TILE(t + 1, 1);
  }

  // ---- epilogue: out = acc * sx[row] * (sw[col]*wscale) + bias ----
  const float wsc = wscale_p[0];
  float cw[4], bv[4];
#pragma unroll
  for (int ni = 0; ni < 4; ++ni) {
    const int col = n0 + wc * 64 + ni * 16 + r16;
    cw[ni] = sw[col] * wsc;
    bv[ni] = bias[col];
  }
#pragma unroll
  for (int mi = 0; mi < 4; ++mi) {
#pragma unroll
    for (int r = 0; r < 4; ++r) {
      // C/D layout (16x16 shapes, dtype-independent): col = lane&15, row = (lane>>4)*4 + reg
      const int row = m0 + wr * 64 + mi * 16 + kq * 4 + r;
      const float sxr = sx[row];
      float* cp = C + (size_t)row * Nn + (n0 + wc * 64 + r16);
#pragma unroll
      for (int ni = 0; ni < 4; ++ni)
        cp[ni * 16] = (float)acc[mi][ni][r] * (sxr * cw[ni]) + bv[ni];
    }
  }
#undef STAGE1
#undef LDFA
#undef LDFB
#undef MFMA16
#undef MFMA8
#undef TILE
}

extern "C" void kernel_launch(void* const* d_in, const int* in_sizes, int n_in,
                              void* d_out, int out_size, void* d_ws, size_t ws_size,
                              hipStream_t stream) {
  (void)n_in; (void)out_size; (void)ws_size;
  const float* x  = (const float*)d_in[0];   // [M][K] fp32
  const float* w  = (const float*)d_in[1];   // [N][K] fp32 (fp8-representable values)
  const float* sc = (const float*)d_in[2];   // [1]
  const float* bs = (const float*)d_in[3];   // [N]
  float* out = (float*)d_out;                // [M][N] fp32

  const int N = in_sizes[3];        // 16384
  const int K = in_sizes[1] / N;    // 4096
  const int M = in_sizes[0] / K;    // 8192

  signed char* xq = (signed char*)d_ws;            // [M][K] i8  (32 MB)
  signed char* wq = xq + (size_t)M * K;            // [N][K] i8  (64 MB)
  float* sxp = (float*)(wq + (size_t)N * K);       // [M]
  float* swp = sxp + M;                            // [N]

  quant_rows<<<M + N, 256, 0, stream>>>(x, w, xq, wq, sxp, swp, M, M + N, K);

  const int NT = N / 128;                          // 128
  const int nwg = (M / 128) * NT;                  // 8192, % 8 == 0
  gemm_i8_2wg<<<nwg, 256, 0, stream>>>(xq, wq, sxp, swp, sc, bs, out, N, K, NT);
}

// Round 19
// 619.439 us; speedup vs baseline: 1.3154x; 1.3154x over previous
//
#include <hip/hip_runtime.h>
#include <stdint.h>

typedef unsigned int u32;
using i32x4 = __attribute__((ext_vector_type(4))) int;

// async global->LDS, 16B per lane, dest = wave-uniform base + lane*16
#define GLD_LDS16(SRC, DST)                                      \
  __builtin_amdgcn_global_load_lds(                              \
      (const __attribute__((address_space(1))) void*)(SRC),      \
      (__attribute__((address_space(3))) void*)(DST), 16, 0, 0)

#define SCHED0() __builtin_amdgcn_sched_barrier(0)
#define BAR()    __builtin_amdgcn_s_barrier()
#define PRIO(x)  __builtin_amdgcn_s_setprio(x)

// ---------- pass 1: per-row symmetric int8 quant (x rows, then w rows) ----------
__global__ __launch_bounds__(256)
void quant_rows(const float* __restrict__ x, const float* __restrict__ w,
                signed char* __restrict__ xq, signed char* __restrict__ wq,
                float* __restrict__ sx, float* __restrict__ sw,
                int Mrows, int totRows, int K) {
  __shared__ float red[4];
  for (int row = blockIdx.x; row < totRows; row += gridDim.x) {
    const bool isx = row < Mrows;
    const float* src = isx ? x + (size_t)row * K : w + (size_t)(row - Mrows) * K;
    const float4* s4 = reinterpret_cast<const float4*>(src) + threadIdx.x * 4;
    float4 v[4];
#pragma unroll
    for (int g = 0; g < 4; ++g) v[g] = s4[g];
    float am = 0.f;
#pragma unroll
    for (int g = 0; g < 4; ++g)
      am = fmaxf(am, fmaxf(fmaxf(fabsf(v[g].x), fabsf(v[g].y)),
                           fmaxf(fabsf(v[g].z), fabsf(v[g].w))));
#pragma unroll
    for (int m = 1; m <= 32; m <<= 1) am = fmaxf(am, __shfl_xor(am, m));
    if ((threadIdx.x & 63) == 0) red[threadIdx.x >> 6] = am;
    __syncthreads();
    am = fmaxf(fmaxf(red[0], red[1]), fmaxf(red[2], red[3]));
    const float s   = am > 0.f ? am * (1.f / 127.f) : 1.f;
    const float inv = am > 0.f ? 127.f / am : 0.f;
    u32 pk[4];
#pragma unroll
    for (int g = 0; g < 4; ++g) {
      const float* vp = reinterpret_cast<const float*>(&v[g]);
      u32 p = 0;
#pragma unroll
      for (int e = 0; e < 4; ++e) {
        int q = (int)rintf(vp[e] * inv);
        q = q < -127 ? -127 : (q > 127 ? 127 : q);
        p |= ((u32)(q & 0xff)) << (8 * e);
      }
      pk[g] = p;
    }
    signed char* dst = (isx ? xq + (size_t)row * K : wq + (size_t)(row - Mrows) * K)
                       + threadIdx.x * 16;
    *reinterpret_cast<uint4*>(dst) = make_uint4(pk[0], pk[1], pk[2], pk[3]);
    if (threadIdx.x == 0) { if (isx) sx[row] = s; else sw[row - Mrows] = s; }
    __syncthreads();
  }
}

// ---------- pass 2: int8 GEMM BK=128, r9 geometry + TWO-CLASS ANTI-PHASE WAVES ----------
// Geometry/swizzle/ledger identical to proven r9 (absmax bit-stable 0.1015625, 0
// conflicts): 256x256 tile, 8 waves (2Mx4N), 128x64/wave, LDS [2][2][256*128]=128KiB,
// phys_slot = (ks*4+kq)^(row&7). NEW: waves 0-3 (class A, wr=0) run r9's phase order
// (reads lead); waves 4-7 (class B, wr=1) run a dependency-equivalent rotation (MFMA
// cluster leads P0, loads lead P1). Waves w and w+4 share a SIMD -> each SIMD holds
// one wave of each class -> while one issues ds_reads the other occupies the matrix
// pipe (m114 co-scheduling), breaking the in-phase serialization that held MfmaUtil
// at 52%. Both classes execute identical VMEM/ds ops per phase with the same gate
// placement -> per-wave vmcnt ledger and WAR barrier distances unchanged from r9.
__global__ __launch_bounds__(512, 2)
void gemm_i8_2cls(const signed char* __restrict__ A,   // [M][K] i8
                  const signed char* __restrict__ B,   // [N][K] i8
                  const float* __restrict__ sx,        // [M]
                  const float* __restrict__ sw,        // [N]
                  const float* __restrict__ wscale_p,  // [1]
                  const float* __restrict__ bias,      // [N]
                  float* __restrict__ C,               // [M][N] fp32
                  int Nn, int Kk, int NT) {
  __shared__ signed char lds[2][2][256 * 128];

  const int tid  = threadIdx.x;
  const int lane = tid & 63;
  const int wave = tid >> 6;       // 0..7
  const int wr = wave >> 2;        // 0..1 (M)  == class (A=0, B=1)
  const int wc = wave & 3;         // 0..3 (N)

  // T1: XCD-aware swizzle (gridDim.x == 2048, divisible by 8)
  const int bid = blockIdx.x;
  const int cpx = gridDim.x >> 3;
  const int wg  = (bid & 7) * cpx + (bid >> 3);
  const int mt = wg / NT, nt = wg % NT;
  const int m0 = mt * 256, n0 = nt * 256;

  // staging: per gload instr, 64 lanes = 8 rows x 128B; lane l -> row l>>3, slot l&7
  const int srow = lane >> 3;
  const int ss   = (lane & 7) ^ (srow & 7);   // inverse-swizzled source k-slot
  const int r16  = lane & 15;
  const int kq   = lane >> 4;

  const signed char* ga = A + ((size_t)m0 + wave * 32 + srow) * Kk + ss * 16;
  const signed char* gb = B + ((size_t)n0 + wave * 32 + srow) * Kk + ss * 16;

  // fragment byte offsets: row*128 + ((kq ^ (row&7))<<4); ks=1 flips byte bit 6
  const int aoff = (wr * 128 + r16) * 128 + ((kq ^ (r16 & 7)) << 4);
  const int boff = (wc * 64  + r16) * 128 + ((kq ^ (r16 & 7)) << 4);

  i32x4 acc[8][4];
#pragma unroll
  for (int i = 0; i < 8; ++i)
#pragma unroll
    for (int j = 0; j < 4; ++j)
      acc[i][j] = (i32x4){0, 0, 0, 0};

  i32x4 afA[4], afB[4];   // A frag sets (roles rotate across clusters)
  i32x4 bP[4], bQ[4];     // B frags ks0 / ks1

#define STAGE128(bfi_, op_, kt_) do {                                           \
    const signed char* _g = ((op_) ? gb : ga) + (size_t)(kt_) * 128;            \
    signed char* _d = &lds[bfi_][op_][wave * 32 * 128];                         \
    GLD_LDS16(_g,                    _d);                                       \
    GLD_LDS16(_g + (size_t)8  * Kk,  _d + 1024);                                \
    GLD_LDS16(_g + (size_t)16 * Kk,  _d + 2048);                                \
    GLD_LDS16(_g + (size_t)24 * Kk,  _d + 3072);                                \
  } while (0)

#define LDFA(AF_, la_, mh_, ks_) do {                                           \
    _Pragma("unroll") for (int _i = 0; _i < 4; ++_i)                            \
      AF_[_i] = *reinterpret_cast<const i32x4*>(                                \
          (la_) + ((aoff + ((mh_) * 4 + _i) * 2048) ^ ((ks_) << 6)));           \
  } while (0)

#define LDFB(BF_, lb_, ks_) do {                                                \
    _Pragma("unroll") for (int _n = 0; _n < 4; ++_n)                            \
      BF_[_n] = *reinterpret_cast<const i32x4*>(                                \
          (lb_) + ((boff + _n * 2048) ^ ((ks_) << 6)));                         \
  } while (0)

#define MFMAC(mh_, AF_, BF_)                                                    \
  _Pragma("unroll") for (int i = 0; i < 4; ++i)                                 \
  _Pragma("unroll") for (int n = 0; n < 4; ++n)                                 \
    acc[(mh_) * 4 + i][n] = __builtin_amdgcn_mfma_i32_16x16x64_i8(              \
        AF_[i], BF_[n], acc[(mh_) * 4 + i][n], 0, 0, 0)

  const int KT = Kk >> 7;   // K/128 = 32

  // ---- prologue: t0->buf0, t1->buf1; drain t0; pre-read t0 frags ----
  STAGE128(0, 0, 0); STAGE128(0, 1, 0);
  STAGE128(1, 0, 1); STAGE128(1, 1, 1);
  asm volatile("s_waitcnt vmcnt(8)" ::: "memory");
  SCHED0(); BAR(); SCHED0();
  LDFA(afA, (const signed char*)&lds[0][0][0], 0, 0);
  LDFB(bP,  (const signed char*)&lds[0][1][0], 0);
  LDFB(bQ,  (const signed char*)&lds[0][1][0], 1);

  // Class A tile: r9 verbatim (reads lead each phase)
#define TILE_A(t_, CUR_) do {                                                   \
    const signed char* laC = &lds[CUR_][0][0];                                  \
    const signed char* laN = &lds[(CUR_) ^ 1][0][0];                            \
    const signed char* lbN = &lds[(CUR_) ^ 1][1][0];                            \
    const int kt2 = ((t_) + 2 < KT) ? (t_) + 2 : KT - 1;                        \
    /* P0 */                                                                    \
    SCHED0(); BAR(); SCHED0();                                                  \
    LDFA(afB, laC, 1, 0);                                                       \
    PRIO(1); MFMAC(0, afA, bP); PRIO(0);      /* C1 */                          \
    LDFA(afA, laC, 0, 1);                                                       \
    STAGE128(CUR_, 1, kt2);                                                     \
    PRIO(1); MFMAC(1, afB, bP); PRIO(0);      /* C2 */                          \
    LDFA(afB, laC, 1, 1);                                                       \
    SCHED0();                                                                   \
    asm volatile("s_waitcnt vmcnt(4)" ::: "memory");                            \
    /* P1 */                                                                    \
    SCHED0(); BAR(); SCHED0();                                                  \
    PRIO(1); MFMAC(0, afA, bQ); PRIO(0);      /* C3 */                          \
    LDFA(afA, laN, 0, 0);                                                       \
    LDFB(bP, lbN, 0);                                                           \
    STAGE128(CUR_, 0, kt2);                                                     \
    PRIO(1); MFMAC(1, afB, bQ); PRIO(0);      /* C4 */                          \
    LDFB(bQ, lbN, 1);                                                           \
  } while (0)

  // Class B tile: dependency-equivalent rotation (MFMA leads P0, loads lead P1).
  // Same ops, same gate position -> identical per-wave ledger & WAR distances.
#define TILE_B(t_, CUR_) do {                                                   \
    const signed char* laC = &lds[CUR_][0][0];                                  \
    const signed char* laN = &lds[(CUR_) ^ 1][0][0];                            \
    const signed char* lbN = &lds[(CUR_) ^ 1][1][0];                            \
    const int kt2 = ((t_) + 2 < KT) ? (t_) + 2 : KT - 1;                        \
    /* P0: MFMA leads (C1 operands were read in prev P1) */                     \
    SCHED0(); BAR(); SCHED0();                                                  \
    PRIO(1); MFMAC(0, afA, bP); PRIO(0);      /* C1 */                          \
    LDFA(afB, laC, 1, 0);                                                       \
    LDFA(afA, laC, 0, 1);                                                       \
    STAGE128(CUR_, 1, kt2);                                                     \
    PRIO(1); MFMAC(1, afB, bP); PRIO(0);      /* C2 */                          \
    LDFA(afB, laC, 1, 1);                                                       \
    SCHED0();                                                                   \
    asm volatile("s_waitcnt vmcnt(4)" ::: "memory");                            \
    /* P1: loads lead (bP dead after P0; stage-A same barrier distance) */      \
    SCHED0(); BAR(); SCHED0();                                                  \
    LDFB(bP, lbN, 0);                                                           \
    STAGE128(CUR_, 0, kt2);                                                     \
    PRIO(1); MFMAC(0, afA, bQ); PRIO(0);      /* C3 */                          \
    LDFA(afA, laN, 0, 0);                                                       \
    PRIO(1); MFMAC(1, afB, bQ); PRIO(0);      /* C4 */                          \
    LDFB(bQ, lbN, 1);                                                           \
  } while (0)

  if (wr == 0) {
    for (int t = 0; t < KT; t += 2) { TILE_A(t, 0); TILE_A(t + 1, 1); }
  } else {
    for (int t = 0; t < KT; t += 2) { TILE_B(t, 0); TILE_B(t + 1, 1); }
  }

  // ---- epilogue: out = acc * sx[row] * (sw[col]*wscale) + bias ----
  const float wsc = wscale_p[0];
  float cw[4], bv[4];
#pragma unroll
  for (int ni = 0; ni < 4; ++ni) {
    const int col = n0 + wc * 64 + ni * 16 + r16;
    cw[ni] = sw[col] * wsc;
    bv[ni] = bias[col];
  }
#pragma unroll
  for (int mi = 0; mi < 8; ++mi) {
#pragma unroll
    for (int r = 0; r < 4; ++r) {
      // C/D layout (16x16 shapes, dtype-independent): col = lane&15, row = (lane>>4)*4 + reg
      const int row = m0 + wr * 128 + mi * 16 + kq * 4 + r;
      const float sxr = sx[row];
      float* cp = C + (size_t)row * Nn + (n0 + wc * 64 + r16);
#pragma unroll
      for (int ni = 0; ni < 4; ++ni)
        cp[ni * 16] = (float)acc[mi][ni][r] * (sxr * cw[ni]) + bv[ni];
    }
  }
#undef STAGE128
#undef LDFA
#undef LDFB
#undef MFMAC
#undef TILE_A
#undef TILE_B
}

extern "C" void kernel_launch(void* const* d_in, const int* in_sizes, int n_in,
                              void* d_out, int out_size, void* d_ws, size_t ws_size,
                              hipStream_t stream) {
  (void)n_in; (void)out_size; (void)ws_size;
  const float* x  = (const float*)d_in[0];   // [M][K] fp32
  const float* w  = (const float*)d_in[1];   // [N][K] fp32 (fp8-representable values)
  const float* sc = (const float*)d_in[2];   // [1]
  const float* bs = (const float*)d_in[3];   // [N]
  float* out = (float*)d_out;                // [M][N] fp32

  const int N = in_sizes[3];        // 16384
  const int K = in_sizes[1] / N;    // 4096
  const int M = in_sizes[0] / K;    // 8192

  signed char* xq = (signed char*)d_ws;            // [M][K] i8  (32 MB)
  signed char* wq = xq + (size_t)M * K;            // [N][K] i8  (64 MB)
  float* sxp = (float*)(wq + (size_t)N * K);       // [M]
  float* swp = sxp + M;                            // [N]

  quant_rows<<<M + N, 256, 0, stream>>>(x, w, xq, wq, sxp, swp, M, M + N, K);

  const int NT = N / 256;
  const int nwg = (M / 256) * NT;                  // 2048, % 8 == 0
  gemm_i8_2cls<<<nwg, 512, 0, stream>>>(xq, wq, sxp, swp, sc, bs, out, N, K, NT);
}